// Round 1
// baseline (306.998 us; speedup 1.0000x reference)
//
#include <hip/hip_runtime.h>

#define TT 256
#define CC 256
#define LLAB 64
#define NEGF -1e30f
#define EPSF 1e-7f

__device__ __forceinline__ float lse2f(float a, float b) {
    float m = fmaxf(a, b);
    return m + __logf(__expf(a - m) + __expf(b - m));
}
__device__ __forceinline__ float lse3f(float a, float b, float c) {
    float m = fmaxf(fmaxf(a, b), c);
    return m + __logf(__expf(a - m) + __expf(b - m) + __expf(c - m));
}

// One wave (64 lanes) per batch item. Lane l owns extended states 2l (blank)
// and 2l+1 (labels[l]); lane 63 additionally owns state 128 (blank) in s2.
// Cross-lane dependency per step is only alpha[2l-1] -> one shfl_up, no LDS,
// no barriers. Emit values prefetched 4 timesteps ahead; their logs computed
// one step early, off the serial critical path.
extern "C" __global__ __launch_bounds__(64) void ctc_fwd(
    const float* __restrict__ y_pred,
    const int* __restrict__ labels,
    const int* __restrict__ input_length,
    const int* __restrict__ label_length,
    float* __restrict__ out)
{
    const int b = blockIdx.x;
    const int l = threadIdx.x;

    const float* __restrict__ yp = y_pred + (size_t)b * (TT * CC);
    const int lab  = labels[b * LLAB + l];
    const int labp = __shfl_up(lab, 1);
    const bool skip_ok = (l >= 1) && (lab != labp);   // allow_skip for state 2l+1

    int len = input_length[b];
    len = len < 1 ? 1 : (len > TT ? TT : len);

    const float* __restrict__ pb = yp + (CC - 1);  // blank column
    const float* __restrict__ pl = yp + lab;       // this lane's label column

    // t = 0 init
    float eb0 = __logf(pb[0] + EPSF);
    float el0 = __logf(pl[0] + EPSF);
    float s0 = (l == 0) ? eb0 : NEGF;   // alpha[2l]
    float s1 = (l == 0) ? el0 : NEGF;   // alpha[2l+1]
    float s2 = NEGF;                    // alpha[128] (meaningful on lane 63 only)

    // Prefetch ring: raw emit values for t = 1..4 (clamped to len-1)
    auto off = [&](int t) { int tt = t < len ? t : len - 1; return (size_t)tt * CC; };
    float rb0 = pb[off(1)], rl0 = pl[off(1)];
    float rb1 = pb[off(2)], rl1 = pl[off(2)];
    float rb2 = pb[off(3)], rl2 = pl[off(3)];
    float rb3 = pb[off(4)], rl3 = pl[off(4)];
    float ebc = __logf(rb0 + EPSF);     // emit logs for the t about to run
    float elc = __logf(rl0 + EPSF);

    for (int t = 1; t < len; ++t) {
        // issue prefetch for t+4 (overlaps with this step's compute chain)
        size_t o = off(t + 4);
        float nb = pb[o], nl = pl[o];

        float am1 = __shfl_up(s1, 1);          // alpha[2l-1]
        if (l == 0) am1 = NEGF;
        float n0 = lse2f(s0, am1) + ebc;                               // state 2l (blank, no skip)
        float n1 = lse3f(s1, s0, skip_ok ? am1 : NEGF) + elc;          // state 2l+1
        float n2 = lse2f(s2, s1) + ebc;                                // state 128 (lane 63)
        s0 = n0; s1 = n1; s2 = n2;

        // rotate ring; compute next step's emit logs off the critical path
        rb0 = rb1; rb1 = rb2; rb2 = rb3; rb3 = nb;
        rl0 = rl1; rl1 = rl2; rl2 = rl3; rl3 = nl;
        ebc = __logf(rb0 + EPSF);
        elc = __logf(rl0 + EPSF);
    }

    int ll = label_length[b];
    ll = ll < 1 ? 1 : (ll > LLAB ? LLAB : ll);
    // final states: 2*ll-1 (odd -> slot1 of lane ll-1), 2*ll (even -> slot0 of lane ll,
    // or state 128 = slot2 of lane 63 when ll == 64)
    float v1 = __shfl(s1, ll - 1);
    float v2 = (ll < LLAB) ? __shfl(s0, ll) : __shfl(s2, 63);
    if (l == 0) out[b] = -lse2f(v1, v2);
}

extern "C" void kernel_launch(void* const* d_in, const int* in_sizes, int n_in,
                              void* d_out, int out_size, void* d_ws, size_t ws_size,
                              hipStream_t stream) {
    const float* y_pred       = (const float*)d_in[0];
    const int*   labels       = (const int*)d_in[1];
    const int*   input_length = (const int*)d_in[2];
    const int*   label_length = (const int*)d_in[3];
    float* out = (float*)d_out;

    const int B = in_sizes[2];  // input_length has one entry per batch item
    ctc_fwd<<<dim3(B), dim3(64), 0, stream>>>(y_pred, labels, input_length, label_length, out);
}

// Round 2
// 241.640 us; speedup vs baseline: 1.2705x; 1.2705x over previous
//
#include <hip/hip_runtime.h>

#define TT 256
#define CC 256
#define LLAB 64
#define SROW 128          // packed emit row: [blank, lab0, blank, lab1, ...] (states 0..127)
#define NEGF -1e30f
#define EPSF 1e-7f
#define DPTH 16           // prefetch depth (statically indexed ring)

__device__ __forceinline__ float lse2f(float a, float b) {
    float m = fmaxf(a, b);
    return m + __logf(__expf(a - m) + __expf(b - m));
}
__device__ __forceinline__ float lse3f(float a, float b, float c) {
    float m = fmaxf(fmaxf(a, b), c);
    return m + __logf(__expf(a - m) + __expf(b - m) + __expf(c - m));
}

// Kernel 1: gather + log. One wave per (b, t). Lane l writes packed float2
// {log(blank), log(label_l)} -> ws[b][t][2l..2l+1]. Massive TLP hides the
// scattered 4B gathers. Rows t >= input_length are never read by kernel 2.
extern "C" __global__ __launch_bounds__(256) void ctc_gather(
    const float* __restrict__ y_pred,
    const int* __restrict__ labels,
    const int* __restrict__ input_length,
    float* __restrict__ ws)
{
    const int b    = blockIdx.y;
    const int wave = threadIdx.x >> 6;
    const int l    = threadIdx.x & 63;
    const int t    = blockIdx.x * 4 + wave;

    int len = input_length[b];
    len = len < 1 ? 1 : (len > TT ? TT : len);
    if (t >= len) return;

    const int lab = labels[b * LLAB + l];
    const float* __restrict__ row = y_pred + ((size_t)b * TT + t) * CC;
    float vb = row[CC - 1];      // broadcast (same addr all lanes)
    float vl = row[lab];         // scattered gather
    float2 w;
    w.x = __logf(vb + EPSF);
    w.y = __logf(vl + EPSF);
    *(float2*)(ws + ((size_t)b * TT + t) * SROW + 2 * l) = w;
}

// Kernel 2: the serial alpha recurrence. One wave per batch item; lane l owns
// states {2l, 2l+1}, lane 63 also state 128 (blank emit == r.x). Per step:
// one coalesced float2 load (prefetched DPTH steps ahead through a statically
// indexed ring -> counted vmcnt, no per-step vmcnt(0)), one shfl_up, lse ops.
extern "C" __global__ __launch_bounds__(64) void ctc_rec(
    const float* __restrict__ ws,
    const int* __restrict__ labels,
    const int* __restrict__ input_length,
    const int* __restrict__ label_length,
    float* __restrict__ out)
{
    const int b = blockIdx.x;
    const int l = threadIdx.x;

    const int lab  = labels[b * LLAB + l];
    const int labp = __shfl_up(lab, 1);
    const bool skip_ok = (l >= 1) && (lab != labp);

    int len = input_length[b];
    len = len < 1 ? 1 : (len > TT ? TT : len);
    const int tmax = len - 1;

    const float* __restrict__ base = ws + (size_t)b * TT * SROW + 2 * l;

    // t = 0
    float2 r0 = *(const float2*)(base);
    float s0 = (l == 0) ? r0.x : NEGF;
    float s1 = (l == 0) ? r0.y : NEGF;
    float s2 = NEGF;

    // preload ring for t = 1..DPTH (clamped)
    float2 ring[DPTH];
#pragma unroll
    for (int j = 0; j < DPTH; ++j) {
        int tt = 1 + j; tt = tt > tmax ? tmax : tt;
        ring[j] = *(const float2*)(base + (size_t)tt * SROW);
    }

    for (int tb = 1; tb < len; tb += DPTH) {
#pragma unroll
        for (int j = 0; j < DPTH; ++j) {
            const int t = tb + j;
            float2 r = ring[j];
            int tp = t + DPTH; tp = tp > tmax ? tmax : tp;
            ring[j] = *(const float2*)(base + (size_t)tp * SROW);

            float am1 = __shfl_up(s1, 1);
            if (l == 0) am1 = NEGF;
            float n0 = lse2f(s0, am1) + r.x;
            float n1 = lse3f(s1, s0, skip_ok ? am1 : NEGF) + r.y;
            float n2 = lse2f(s2, s1) + r.x;
            const bool act = t < len;
            s0 = act ? n0 : s0;
            s1 = act ? n1 : s1;
            s2 = act ? n2 : s2;
        }
    }

    int ll = label_length[b];
    ll = ll < 1 ? 1 : (ll > LLAB ? LLAB : ll);
    float v1 = __shfl(s1, ll - 1);                               // state 2*ll-1
    float v2 = (ll < LLAB) ? __shfl(s0, ll) : __shfl(s2, 63);    // state 2*ll
    if (l == 0) out[b] = -lse2f(v1, v2);
}

extern "C" void kernel_launch(void* const* d_in, const int* in_sizes, int n_in,
                              void* d_out, int out_size, void* d_ws, size_t ws_size,
                              hipStream_t stream) {
    const float* y_pred       = (const float*)d_in[0];
    const int*   labels       = (const int*)d_in[1];
    const int*   input_length = (const int*)d_in[2];
    const int*   label_length = (const int*)d_in[3];
    float* out = (float*)d_out;
    float* ws  = (float*)d_ws;   // needs B*T*SROW*4 = 64 MiB

    const int B = in_sizes[2];

    dim3 g1(TT / 4, B);
    ctc_gather<<<g1, dim3(256), 0, stream>>>(y_pred, labels, input_length, ws);
    ctc_rec<<<dim3(B), dim3(64), 0, stream>>>(ws, labels, input_length, label_length, out);
}